// Round 7
// baseline (84.222 us; speedup 1.0000x reference)
//
#include <hip/hip_runtime.h>
#include <stdint.h>

// Pipeline (k' = (ky*2+kx)*256 + c ordering for the GEMM K axis):
//   0. prep : blocks 0..1023   -> W (1024,256,2,2) fp32 -> Wp[e][p*256+c] bf16 + zero page
//             blocks 1024..5119 -> img (8,256,128,128) fp32 -> imgT[b][y][x][c] bf16
//   1. gemm : 128x128-tile 4-wave MFMA GEMM, A gathered in-staging from imgT,
//             2-deep double-buffered pipeline with counted vmcnt (never 0 in loop).
//      pixel (py,px) <-> (o,p): o=(py>>1)+2*(px>>1), p=(py&1)*2+(px&1)

typedef __attribute__((ext_vector_type(8))) short bf16x8;
typedef __attribute__((ext_vector_type(4))) float f32x4;

#define GAS(p) ((const __attribute__((address_space(1))) void*)(p))
#define LAS(p) ((__attribute__((address_space(3))) void*)(p))

__device__ __forceinline__ unsigned short f2bf(float f) {
    union { float f; uint32_t u; } x; x.f = f;
    uint32_t u = x.u;
    uint32_t r = (u + 0x7FFFu + ((u >> 16) & 1u)) >> 16;   // round-nearest-even
    return (unsigned short)r;
}

// ---------------- Stage 0: fused W-reorder + img transpose ----------------
__global__ __launch_bounds__(256)
void prep_kernel(const float* __restrict__ img, const float* __restrict__ Wf,
                 unsigned short* __restrict__ Wp, unsigned short* __restrict__ zp,
                 unsigned short* __restrict__ imgT) {
    __shared__ unsigned short sT[8192];     // [x:128][cpair:32] uint-packed, swizzled
    const int blk = blockIdx.x;
    const int t = threadIdx.x;

    if (blk < 1024) {                       // ---- wconv: e = blk, c = t ----
        const int e = blk, c = t;
        float4 w4 = *(const float4*)&Wf[(size_t)e * 1024 + c * 4];
        Wp[e * 1024 + 0 * 256 + c] = f2bf(w4.x);   // p = ky*2+kx
        Wp[e * 1024 + 1 * 256 + c] = f2bf(w4.y);
        Wp[e * 1024 + 2 * 256 + c] = f2bf(w4.z);
        Wp[e * 1024 + 3 * 256 + c] = f2bf(w4.w);
        if (e == 0 && c < 32) {
            uint4 z = {0, 0, 0, 0};
            ((uint4*)zp)[c] = z;            // 512 B zeros for OOB staging
        }
        return;
    }

    // ---- imgt: block = (b, y, c-chunk of 64); float4-vectorized reads ----
    const int ib = blk - 1024;              // 0..4095
    const int cc = ib & 3;
    const int y  = (ib >> 2) & 127;
    const int b  = ib >> 9;
    const int xq = t & 31;                  // x-quad: x = xq*4 + j
    const int ch = t >> 5;                  // 0..7 (c-pair subgroup)
    unsigned int* sU = (unsigned int*)sT;
    const size_t pl = ((size_t)b * 256 + cc * 64) * 16384 + (size_t)y * 128;
    #pragma unroll
    for (int it = 0; it < 4; ++it) {
        const int cp = it * 8 + ch;         // c-pair 0..31
        const float4 v0 = *(const float4*)&img[pl + (size_t)(2 * cp)     * 16384 + xq * 4];
        const float4 v1 = *(const float4*)&img[pl + (size_t)(2 * cp + 1) * 16384 + xq * 4];
        const float a0[4] = {v0.x, v0.y, v0.z, v0.w};
        const float a1[4] = {v1.x, v1.y, v1.z, v1.w};
        #pragma unroll
        for (int j = 0; j < 4; ++j) {
            const int x = xq * 4 + j;
            const unsigned int pk = (unsigned)f2bf(a0[j]) | ((unsigned)f2bf(a1[j]) << 16);
            sU[x * 32 + (cp ^ (x & 31))] = pk;
        }
    }
    __syncthreads();
    unsigned short* ob = imgT + (((size_t)b * 128 + y) * 128) * 256 + cc * 64;
    #pragma unroll
    for (int jj = 0; jj < 16; ++jj) {
        const int oo = t + 256 * jj;        // 0..4095
        const int xx = oo >> 5;
        const int c2 = oo & 31;
        const unsigned int pk = sU[xx * 32 + (c2 ^ (xx & 31))];
        *(unsigned int*)&ob[(size_t)xx * 256 + c2 * 2] = pk;
    }
}

// ---------------- Stage 1: fused-gather 128^2 MFMA GEMM, 2-deep pipeline ----------------
// 1024 blocks, 256 threads (4 waves 2x2), BK=64, 16 K-tiles.
// LDS 64 KB (2 buf x (W 16K + A 16K)) -> 2 blocks/CU. XOR swizzle on source + ds_read.
__global__ __launch_bounds__(256)
void gemm_kernel(const unsigned short* __restrict__ Wp,
                 const unsigned short* __restrict__ imgT,
                 const unsigned short* __restrict__ zp,
                 const int* __restrict__ bidx,
                 const int* __restrict__ pxid,
                 const int* __restrict__ pyid,
                 const float* __restrict__ bias,
                 float* __restrict__ out) {
    const int orig = blockIdx.x;                    // 1024
    const int wg = (orig & 7) * 128 + (orig >> 3);  // XCD k <-> batch k (bijective)
    const int et = wg & 7;                          // 8 e-tiles of 128
    const int nt = wg >> 3;                         // 128 gn-tiles of 128
    const int g  = nt >> 2;
    const int n0 = (nt & 3) * 128;
    const int e0 = et * 128;
    const int b = g >> 2, o = g & 3;

    const int tid  = threadIdx.x;
    const int lane = tid & 63;
    const int wid  = tid >> 6;
    const int wr   = wid >> 1;
    const int wc   = wid & 1;

    __shared__ unsigned short sW[2][8192];
    __shared__ unsigned short sA[2][8192];

    // ---- per-thread stage descriptors: rows row0+32r, same chunk cg for all r ----
    const int row0 = tid >> 3;                      // 0..31
    const int cg   = (tid & 7) ^ (row0 & 7);        // (row&7)==(row0&7) since 32r%8==0
    int ay[4], ax[4];
    size_t apl[4];
    #pragma unroll
    for (int r = 0; r < 4; ++r) {
        const int row = row0 + 32 * r;
        const int gi = b * 512 + n0 + row;
        apl[r] = (size_t)bidx[gi] * (128 * 128 * 256);
        ay[r] = 2 * pyid[gi] - 1 + (o & 1) * 2;     // + (p>>1) at stage time
        ax[r] = 2 * pxid[gi] - 1 + (o >> 1) * 2;    // + (p&1)
    }

    const f32x4 fzero = {0.f, 0.f, 0.f, 0.f};
    f32x4 acc[4][4];
    #pragma unroll
    for (int m = 0; m < 4; ++m)
        #pragma unroll
        for (int nf = 0; nf < 4; ++nf) acc[m][nf] = fzero;

    auto stage = [&](int kc, int buf) {
        const int p   = kc >> 2;
        const int csh = (kc & 3) * 64;              // c-chunk offset within pixel row
        #pragma unroll
        for (int r = 0; r < 4; ++r) {
            const int i   = r * 256 + tid;
            const int row = row0 + 32 * r;
            const unsigned short* gw = Wp + (size_t)(e0 + row) * 1024 + kc * 64 + cg * 8;
            __builtin_amdgcn_global_load_lds(GAS(gw), LAS(&sW[buf][i * 8]), 16, 0, 0);
            const int yy = ay[r] + (p >> 1);
            const int xx = ax[r] + (p & 1);
            const unsigned short* ga =
                ((unsigned)yy < 128u && (unsigned)xx < 128u)
                    ? imgT + apl[r] + ((size_t)(yy * 128 + xx)) * 256 + csh + cg * 8
                    : zp + cg * 8;
            __builtin_amdgcn_global_load_lds(GAS(ga), LAS(&sA[buf][i * 8]), 16, 0, 0);
        }
    };

    stage(0, 0);                                    // 8 outstanding
    stage(1, 1);                                    // 16 outstanding
    for (int kt = 0; kt < 16; ++kt) {
        const int cur = kt & 1;
        // tile kt ready; tile kt+1's 8 loads stay in flight (T4: never 0 in loop)
        if (kt == 15) { asm volatile("s_waitcnt vmcnt(0)" ::: "memory"); }
        else          { asm volatile("s_waitcnt vmcnt(8)" ::: "memory"); }
        __builtin_amdgcn_s_barrier();

        #pragma unroll
        for (int ks = 0; ks < 2; ++ks) {
            bf16x8 af[4], bfr[4];
            #pragma unroll
            for (int m = 0; m < 4; ++m) {
                const int row = wr * 64 + m * 16 + (lane & 15);
                const int cl  = (ks * 4 + (lane >> 4)) ^ (row & 7);
                af[m] = *(const bf16x8*)&sW[cur][row * 64 + cl * 8];
            }
            #pragma unroll
            for (int nf = 0; nf < 4; ++nf) {
                const int row = wc * 64 + nf * 16 + (lane & 15);
                const int cl  = (ks * 4 + (lane >> 4)) ^ (row & 7);
                bfr[nf] = *(const bf16x8*)&sA[cur][row * 64 + cl * 8];
            }
            __builtin_amdgcn_s_setprio(1);
            #pragma unroll
            for (int m = 0; m < 4; ++m)
                #pragma unroll
                for (int nf = 0; nf < 4; ++nf)
                    acc[m][nf] = __builtin_amdgcn_mfma_f32_16x16x32_bf16(
                        af[m], bfr[nf], acc[m][nf], 0, 0, 0);
            __builtin_amdgcn_s_setprio(0);
        }

        __builtin_amdgcn_s_barrier();               // all waves done reading buf cur
        if (kt + 2 < 16) stage(kt + 2, cur);        // overwrite cur for tile kt+2
    }

    // ---- epilogue: D row(e) = (lane>>4)*4+reg, col(n) = lane&15 ----
    const int erow_l = (lane >> 4) * 4;
    const int ncol_l = lane & 15;
    #pragma unroll
    for (int m = 0; m < 4; ++m) {
        #pragma unroll
        for (int nf = 0; nf < 4; ++nf) {
            const int nn = n0 + wc * 64 + nf * 16 + ncol_l;
            #pragma unroll
            for (int reg = 0; reg < 4; ++reg) {
                const int e = e0 + wr * 64 + m * 16 + erow_l + reg;
                out[((size_t)g * 1024 + e) * 512 + nn] = acc[m][nf][reg] + bias[e];
            }
        }
    }
}

extern "C" void kernel_launch(void* const* d_in, const int* in_sizes, int n_in,
                              void* d_out, int out_size, void* d_ws, size_t ws_size,
                              hipStream_t stream) {
    const float* img  = (const float*)d_in[0];
    const float* Wf   = (const float*)d_in[1];
    const float* bias = (const float*)d_in[2];
    const int*   bidx = (const int*)d_in[3];
    const int*   pxid = (const int*)d_in[4];
    const int*   pyid = (const int*)d_in[5];
    float* out = (float*)d_out;

    unsigned short* Wp   = (unsigned short*)((char*)d_ws + (32u << 20));  // 2 MiB
    unsigned short* zp   = (unsigned short*)((char*)d_ws + (36u << 20));  // 512 B zeros
    unsigned short* imgT = (unsigned short*)((char*)d_ws + (64u << 20));  // 64 MiB

    hipLaunchKernelGGL(prep_kernel, dim3(5120), dim3(256), 0, stream,
                       img, Wf, Wp, zp, imgT);
    hipLaunchKernelGGL(gemm_kernel, dim3(1024), dim3(256), 0, stream,
                       Wp, imgT, zp, bidx, pxid, pyid, bias, out);
}

// Round 8
// 79.666 us; speedup vs baseline: 1.0572x; 1.0572x over previous
//
#include <hip/hip_runtime.h>
#include <stdint.h>

// Pipeline (k' = (ky*2+kx)*256 + c ordering for the GEMM K axis):
//   0. prep : blocks 0..511    -> W fp32 -> Wq in GEMM-staging order (chunk-major) bf16
//             blocks 512..4607 -> img (8,256,128,128) fp32 -> imgT[b][y][x][c] bf16
//   1. gemm : 256x256-tile 8-wave MFMA GEMM, 8-phase schedule, counted vmcnt(4)
//             (never 0 in loop), A gathered in-staging from imgT per keypoint.
//      pixel (py,px) <-> (o,p): o=(py>>1)+2*(px>>1), p=(py&1)*2+(px&1)
// Wq layout: [et:4][j:16][h:2][chunk:4][row:256][8 k] so a staging inst reads
//   8 KB fully coalesced and ds_read af is bank-conflict-free (bank = row*4).

typedef __attribute__((ext_vector_type(8))) short bf16x8;
typedef __attribute__((ext_vector_type(4))) float f32x4;

#define GAS(p) ((const __attribute__((address_space(1))) void*)(p))
#define LAS(p) ((__attribute__((address_space(3))) void*)(p))

__device__ __forceinline__ unsigned short f2bf(float f) {
    union { float f; uint32_t u; } x; x.f = f;
    uint32_t u = x.u;
    uint32_t r = (u + 0x7FFFu + ((u >> 16) & 1u)) >> 16;   // round-nearest-even
    return (unsigned short)r;
}

// ---------------- Stage 0: fused W-reorder (staging order) + img transpose ----------------
__global__ __launch_bounds__(256)
void prep_kernel(const float* __restrict__ img, const float* __restrict__ Wf,
                 unsigned short* __restrict__ Wq, unsigned short* __restrict__ zp,
                 unsigned short* __restrict__ imgT) {
    __shared__ unsigned short sT[8192];
    const int blk = blockIdx.x;
    const int tid = threadIdx.x;

    if (blk < 512) {                        // ---- Wq: one thread = 8 k's of one (et,j,h,chunk,row)
        if (blk == 0 && tid < 32) {
            uint4 z = {0, 0, 0, 0};
            ((uint4*)zp)[tid] = z;          // 512 B zeros for OOB staging
        }
        const int t  = blk * 256 + tid;     // 0..131071
        const int et = t >> 15;
        const int r1 = t & 32767;
        const int j  = r1 >> 11;
        const int r2 = r1 & 2047;
        const int h  = r2 >> 10;
        const int r3 = r2 & 1023;
        const int chunk = r3 >> 8;
        const int row   = r3 & 255;
        const int e  = et * 256 + row;
        const int kb = j * 64 + h * 32 + chunk * 8;
        unsigned short v[8];
        #pragma unroll
        for (int kk = 0; kk < 8; ++kk) {
            const int k = kb + kk;          // k' in [0,1024)
            const int c = k & 255;
            const int p = k >> 8;
            v[kk] = f2bf(Wf[(size_t)e * 1024 + c * 4 + p]);
        }
        *(uint4*)&Wq[(size_t)t * 8] = *(const uint4*)v;
        return;
    }

    // ---- imgt: block = (b, y, c-chunk of 64); float4-vectorized reads ----
    const int ib = blk - 512;               // 0..4095
    const int cc = ib & 3;
    const int y  = (ib >> 2) & 127;
    const int b  = ib >> 9;
    const int xq = tid & 31;                // x-quad: x = xq*4 + jj
    const int ch = tid >> 5;                // 0..7 (c-pair subgroup)
    unsigned int* sU = (unsigned int*)sT;
    const size_t pl = ((size_t)b * 256 + cc * 64) * 16384 + (size_t)y * 128;
    #pragma unroll
    for (int it = 0; it < 4; ++it) {
        const int cp = it * 8 + ch;         // c-pair 0..31
        const float4 v0 = *(const float4*)&img[pl + (size_t)(2 * cp)     * 16384 + xq * 4];
        const float4 v1 = *(const float4*)&img[pl + (size_t)(2 * cp + 1) * 16384 + xq * 4];
        const float a0[4] = {v0.x, v0.y, v0.z, v0.w};
        const float a1[4] = {v1.x, v1.y, v1.z, v1.w};
        #pragma unroll
        for (int jj = 0; jj < 4; ++jj) {
            const int x = xq * 4 + jj;
            const unsigned int pk = (unsigned)f2bf(a0[jj]) | ((unsigned)f2bf(a1[jj]) << 16);
            sU[x * 32 + (cp ^ (x & 31))] = pk;
        }
    }
    __syncthreads();
    unsigned short* ob = imgT + (((size_t)b * 128 + y) * 128) * 256 + cc * 64;
    #pragma unroll
    for (int jj = 0; jj < 16; ++jj) {
        const int oo = tid + 256 * jj;      // 0..4095
        const int xx = oo >> 5;
        const int c2 = oo & 31;
        const unsigned int pk = sU[xx * 32 + (c2 ^ (xx & 31))];
        *(unsigned int*)&ob[(size_t)xx * 256 + c2 * 2] = pk;
    }
}

// ---------------- Stage 1: fused-gather 256^2 8-phase MFMA GEMM ----------------
// 256 blocks (1/CU), 512 threads (8 waves 2m x 4n). 16 K-tiles of BK=64,
// each tile = 2 K-halves; per half: vmcnt(4)+barrier, issue next-tile half's
// 4 staging insts, ds_read af[8] (W, conflict-free), then 2 phases of
// {ds_read bf[2] (A), setprio, 16 MFMA, setprio}. In-flight 4-8, never 0.
__global__ __launch_bounds__(512, 1)
void gemm_kernel(const unsigned short* __restrict__ Wq,
                 const unsigned short* __restrict__ imgT,
                 const unsigned short* __restrict__ zp,
                 const int* __restrict__ bidx,
                 const int* __restrict__ pxid,
                 const int* __restrict__ pyid,
                 const float* __restrict__ bias,
                 float* __restrict__ out)
{
    const int orig = blockIdx.x;            // 256
    const int xcd  = orig & 7;
    const int s    = orig >> 3;             // 0..31
    const int gnt  = xcd * 8 + (s >> 2);    // 64 gn-tiles of 256; e-siblings share XCD
    const int et   = s & 3;                 // 4 e-tiles of 256
    const int e0   = et * 256;
    const int g    = gnt >> 1;
    const int n0   = (gnt & 1) * 256;
    const int b = g >> 2, o = g & 3;

    const int tid  = threadIdx.x;
    const int lane = tid & 63;
    const int wid  = tid >> 6;
    const int wm   = wid >> 2;              // 0..1 -> e rows wm*128
    const int wn   = wid & 3;               // 0..3 -> n cols wn*64

    __shared__ unsigned short sW[2 * 16384]; // [buf][h:2][chunk:4][row:256][8]
    __shared__ unsigned short sA[2 * 16384]; // [buf][h:2][row:256][slot:4][8]

    // ---- A stage descriptors: thread -> rows u*128 + tid/4, 16B chunk (tid&3) ----
    int ayv[2], axv[2];
    size_t apl[2];
    #pragma unroll
    for (int u = 0; u < 2; ++u) {
        const int row = u * 128 + (tid >> 2);
        const int gi = b * 512 + n0 + row;
        apl[u] = (size_t)bidx[gi] * (128 * 128 * 256);
        ayv[u] = 2 * pyid[gi] - 1 + (o & 1) * 2;   // + (p>>1) at stage time
        axv[u] = 2 * pxid[gi] - 1 + (o >> 1) * 2;  // + (p&1)
    }
    const int aswz = (((tid & 3) ^ ((tid >> 3) & 3))) * 8;  // pre-swizzled chunk (shorts)
    const unsigned short* wq_base = Wq + (size_t)et * 262144 + tid * 8;

    f32x4 acc[8][4];
    #pragma unroll
    for (int m = 0; m < 8; ++m)
        #pragma unroll
        for (int nf = 0; nf < 4; ++nf) acc[m][nf] = (f32x4){0.f, 0.f, 0.f, 0.f};

    auto stageHalf = [&](int j, int h, int buf) {
        // W: 2 insts, fully coalesced from Wq staging order
        #pragma unroll
        for (int u = 0; u < 2; ++u) {
            const unsigned short* src = wq_base + (size_t)(j * 2 + h) * 8192 + u * 4096;
            __builtin_amdgcn_global_load_lds(GAS(src),
                LAS(&sW[buf * 16384 + h * 8192 + u * 4096 + tid * 8]), 16, 0, 0);
        }
        // A: 2 insts, 64B-aligned segments per keypoint row, swizzled source
        const int p = j >> 2;
        const int csh = (j & 3) * 64 + h * 32 + aswz;
        #pragma unroll
        for (int u = 0; u < 2; ++u) {
            const int yy = ayv[u] + (p >> 1);
            const int xx = axv[u] + (p & 1);
            const unsigned short* src =
                ((unsigned)yy < 128u && (unsigned)xx < 128u)
                    ? imgT + apl[u] + ((size_t)(yy * 128 + xx)) * 256 + csh
                    : zp + aswz;
            __builtin_amdgcn_global_load_lds(GAS(src),
                LAS(&sA[buf * 16384 + h * 8192 + u * 4096 + tid * 8]), 16, 0, 0);
        }
    };

    // prologue: tile 0 fully staged (8 insts in flight)
    stageHalf(0, 0, 0);
    stageHalf(0, 1, 0);

    for (int j = 0; j < 16; ++j) {
        const int buf = j & 1;
        #pragma unroll
        for (int h = 0; h < 2; ++h) {
            // complete the oldest half (tile j, half h); keep the rest in flight
            if (j == 15 && h == 1) { asm volatile("s_waitcnt vmcnt(0)" ::: "memory"); }
            else                   { asm volatile("s_waitcnt vmcnt(4)" ::: "memory"); }
            __builtin_amdgcn_s_barrier();
            if (j < 15) stageHalf(j + 1, h, buf ^ 1);   // 4 insts into the other dbuf

            // W fragments for this K-half (reused across both n-half phases)
            bf16x8 af[8];
            {
                const int chunk = lane >> 4;
                const int rb = wm * 128 + (lane & 15);
                #pragma unroll
                for (int m = 0; m < 8; ++m)
                    af[m] = *(const bf16x8*)&sW[buf * 16384 + h * 8192 + chunk * 2048 + (rb + m * 16) * 8];
            }
            #pragma unroll
            for (int nh = 0; nh < 2; ++nh) {
                bf16x8 bfr[2];
                #pragma unroll
                for (int nn = 0; nn < 2; ++nn) {
                    const int row = wn * 64 + (nh * 2 + nn) * 16 + (lane & 15);
                    const int perm = (lane >> 4) ^ ((row >> 1) & 3);
                    bfr[nn] = *(const bf16x8*)&sA[buf * 16384 + h * 8192 + row * 32 + perm * 8];
                }
                __builtin_amdgcn_s_setprio(1);
                #pragma unroll
                for (int m = 0; m < 8; ++m)
                    #pragma unroll
                    for (int nn = 0; nn < 2; ++nn)
                        acc[m][nh * 2 + nn] = __builtin_amdgcn_mfma_f32_16x16x32_bf16(
                            af[m], bfr[nn], acc[m][nh * 2 + nn], 0, 0, 0);
                __builtin_amdgcn_s_setprio(0);
            }
        }
    }

    // ---- epilogue: D row(e) = (lane>>4)*4+reg, col(n) = lane&15 ----
    #pragma unroll
    for (int m = 0; m < 8; ++m) {
        const int eb = e0 + wm * 128 + m * 16 + (lane >> 4) * 4;
        float bv[4];
        #pragma unroll
        for (int reg = 0; reg < 4; ++reg) bv[reg] = bias[eb + reg];
        #pragma unroll
        for (int nf = 0; nf < 4; ++nf) {
            const int nn = n0 + wn * 64 + nf * 16 + (lane & 15);
            #pragma unroll
            for (int reg = 0; reg < 4; ++reg)
                out[((size_t)g * 1024 + eb + reg) * 512 + nn] = acc[m][nf][reg] + bv[reg];
        }
    }
}

extern "C" void kernel_launch(void* const* d_in, const int* in_sizes, int n_in,
                              void* d_out, int out_size, void* d_ws, size_t ws_size,
                              hipStream_t stream) {
    const float* img  = (const float*)d_in[0];
    const float* Wf   = (const float*)d_in[1];
    const float* bias = (const float*)d_in[2];
    const int*   bidx = (const int*)d_in[3];
    const int*   pxid = (const int*)d_in[4];
    const int*   pyid = (const int*)d_in[5];
    float* out = (float*)d_out;

    unsigned short* Wq   = (unsigned short*)((char*)d_ws + (32u << 20));  // 2 MiB
    unsigned short* zp   = (unsigned short*)((char*)d_ws + (36u << 20));  // 512 B zeros
    unsigned short* imgT = (unsigned short*)((char*)d_ws + (64u << 20));  // 64 MiB

    hipLaunchKernelGGL(prep_kernel, dim3(4608), dim3(256), 0, stream,
                       img, Wf, Wq, zp, imgT);
    hipLaunchKernelGGL(gemm_kernel, dim3(256), dim3(512), 0, stream,
                       Wq, imgT, zp, bidx, pxid, pyid, bias, out);
}